// Round 1
// baseline (250.332 us; speedup 1.0000x reference)
//
#include <hip/hip_runtime.h>
#include <math.h>

// Problem constants (fixed by setup_inputs)
#define BB   32
#define CC   256
#define LL   4096
#define SS   8
#define CS   32
#define NT   256                 // threads per block
#define F4_ROW (LL / 4)          // 1024 float4 per row
#define F4_THR (F4_ROW / NT)     // 4 float4 per thread

__device__ __forceinline__ float gelu_exact(float x) {
    // exact gelu: x * 0.5 * (1 + erf(x / sqrt(2)))
    return 0.5f * x * (1.0f + erff(x * 0.70710678118654752440f));
}

__global__ __launch_bounds__(NT, 4)
void hdconv_encoder_kernel(const float* __restrict__ inp,
                           const float* __restrict__ conv_w,   // [S,3,CS]
                           const float* __restrict__ conv_b,   // [S,CS]
                           const float* __restrict__ ln_g,     // [L]
                           const float* __restrict__ ln_b,     // [L]
                           const float* __restrict__ pw_w,     // [C]
                           const float* __restrict__ pw_b,     // [C]
                           float* __restrict__ out) {
    __shared__ float4 S4[F4_ROW];     // current conv-input row (x_i + y_{i-1})
    __shared__ float  red[8];         // 4 waves x {sum, sumsq}
    __shared__ float  bcast[2];       // {mean, inv_std}

    const int t    = threadIdx.x;
    const int blk  = blockIdx.x;      // [0, B*CS)
    const int b    = blk >> 5;        // batch
    const int c    = blk & 31;        // channel within group (block-uniform)
    const int lane = t & 63;
    const int wave = t >> 6;

    // y_{i-1} for this thread's 16 positions (0 before group 0)
    float y[16];
#pragma unroll
    for (int j = 0; j < 16; ++j) y[j] = 0.0f;

    // LayerNorm gamma/beta are indexed by position l -> load once, reuse x8
    float4 g4[F4_THR], e4[F4_THR];
    const float4* gp = (const float4*)ln_g;
    const float4* ep = (const float4*)ln_b;
#pragma unroll
    for (int k = 0; k < F4_THR; ++k) {
        g4[k] = gp[t + NT * k];
        e4[k] = ep[t + NT * k];
    }

    for (int i = 0; i < SS; ++i) {
        const int ch = i * CS + c;                        // global channel
        const float4* xrow = (const float4*)(inp + ((size_t)(b * CC + ch)) * LL);
        float4*       orow = (float4*)(out + ((size_t)(b * CC + ch)) * LL);

        // ---- stage conv input row: s = x_i + y_{i-1} -> LDS ----
        float4 x4[F4_THR];
#pragma unroll
        for (int k = 0; k < F4_THR; ++k) x4[k] = xrow[t + NT * k];
#pragma unroll
        for (int k = 0; k < F4_THR; ++k) {
            float4 s;
            s.x = x4[k].x + y[4 * k + 0];
            s.y = x4[k].y + y[4 * k + 1];
            s.z = x4[k].z + y[4 * k + 2];
            s.w = x4[k].w + y[4 * k + 3];
            S4[t + NT * k] = s;
        }
        __syncthreads();   // (1) S row fully written before conv reads

        // block-uniform per-(group, c) params -> scalar loads
        const float w0 = conv_w[i * 96 + 0 * CS + c];
        const float w1 = conv_w[i * 96 + 1 * CS + c];
        const float w2 = conv_w[i * 96 + 2 * CS + c];
        const float bb = conv_b[i * CS + c];

        // ---- 3-tap depthwise conv + local LN partial sums ----
        float lsum = 0.0f, lsq = 0.0f;
#pragma unroll
        for (int k = 0; k < F4_THR; ++k) {
            const int f = t + NT * k;
            const float4 cc = S4[f];
            const float sm1 = (f > 0)          ? S4[f - 1].w : 0.0f;  // s[4f-1]
            const float sp4 = (f < F4_ROW - 1) ? S4[f + 1].x : 0.0f;  // s[4f+4]
            float y0 = fmaf(w0, sm1,  fmaf(w1, cc.x, fmaf(w2, cc.y, bb)));
            float y1 = fmaf(w0, cc.x, fmaf(w1, cc.y, fmaf(w2, cc.z, bb)));
            float y2 = fmaf(w0, cc.y, fmaf(w1, cc.z, fmaf(w2, cc.w, bb)));
            float y3 = fmaf(w0, cc.z, fmaf(w1, cc.w, fmaf(w2, sp4, bb)));
            y[4 * k + 0] = y0; y[4 * k + 1] = y1;
            y[4 * k + 2] = y2; y[4 * k + 3] = y3;
            lsum += (y0 + y1) + (y2 + y3);
            lsq  += fmaf(y0, y0, fmaf(y1, y1, fmaf(y2, y2, y3 * y3)));
        }

        // ---- block reduction for this row's LayerNorm stats ----
#pragma unroll
        for (int off = 32; off > 0; off >>= 1) {
            lsum += __shfl_down(lsum, off, 64);
            lsq  += __shfl_down(lsq,  off, 64);
        }
        if (lane == 0) { red[wave * 2] = lsum; red[wave * 2 + 1] = lsq; }
        __syncthreads();   // (2) red[] visible; also orders conv reads vs next S writes
        if (t == 0) {
            const float sum = (red[0] + red[2]) + (red[4] + red[6]);
            const float sq  = (red[1] + red[3]) + (red[5] + red[7]);
            const float mean = sum * (1.0f / LL);
            const float var  = sq * (1.0f / LL) - mean * mean;
            bcast[0] = mean;
            bcast[1] = rsqrtf(var + 1e-6f);
        }
        __syncthreads();   // (3) mean/inv broadcast
        const float mean = bcast[0];
        const float inv  = bcast[1];

        // ---- normalize + pointwise scale/bias + exact gelu + residual ----
        const float pw = pw_w[ch];
        const float pb = pw_b[ch];
#pragma unroll
        for (int k = 0; k < F4_THR; ++k) {
            float4 o;
            float n;
            n   = fmaf((y[4 * k + 0] - mean) * inv, g4[k].x, e4[k].x);
            o.x = x4[k].x + gelu_exact(fmaf(n, pw, pb));
            n   = fmaf((y[4 * k + 1] - mean) * inv, g4[k].y, e4[k].y);
            o.y = x4[k].y + gelu_exact(fmaf(n, pw, pb));
            n   = fmaf((y[4 * k + 2] - mean) * inv, g4[k].z, e4[k].z);
            o.z = x4[k].z + gelu_exact(fmaf(n, pw, pb));
            n   = fmaf((y[4 * k + 3] - mean) * inv, g4[k].w, e4[k].w);
            o.w = x4[k].w + gelu_exact(fmaf(n, pw, pb));
            orow[t + NT * k] = o;
        }
        // next iteration's S4 writes are safe: every thread's conv reads of
        // S4 precede barrier (2) above.
    }
}

extern "C" void kernel_launch(void* const* d_in, const int* in_sizes, int n_in,
                              void* d_out, int out_size, void* d_ws, size_t ws_size,
                              hipStream_t stream) {
    const float* inp    = (const float*)d_in[0];
    const float* conv_w = (const float*)d_in[1];
    const float* conv_b = (const float*)d_in[2];
    const float* ln_g   = (const float*)d_in[3];
    const float* ln_b   = (const float*)d_in[4];
    const float* pw_w   = (const float*)d_in[5];
    const float* pw_b   = (const float*)d_in[6];
    float* out = (float*)d_out;

    dim3 grid(BB * CS);   // 1024 blocks: one per (batch, within-group channel) chain
    dim3 block(NT);
    hdconv_encoder_kernel<<<grid, block, 0, stream>>>(
        inp, conv_w, conv_b, ln_g, ln_b, pw_w, pw_b, out);
}